// Round 6
// baseline (259.763 us; speedup 1.0000x reference)
//
#include <hip/hip_runtime.h>

#define HH 4
#define CC 128
#define NEG_SLOPE 0.2f
#define NPB 8

typedef float v2f __attribute__((ext_vector_type(2)));

static __device__ __forceinline__ v2f pkfma(v2f a, v2f b, v2f c) {
#if __has_builtin(__builtin_elementwise_fma)
    return __builtin_elementwise_fma(a, b, c);
#else
    return (v2f){fmaf(a.x, b.x, c.x), fmaf(a.y, b.y, c.y)};
#endif
}
static __device__ __forceinline__ v2f vabs(v2f u) {
#if __has_builtin(__builtin_elementwise_abs)
    return __builtin_elementwise_abs(u);
#else
    return (v2f){__builtin_fabsf(u.x), __builtin_fabsf(u.y)};
#endif
}

static inline size_t roundup256(size_t x) { return (x + 255) & ~(size_t)255; }

// ---------------- prep: mean(edge_attr) + in-degree hist + weight pack + Lin
// packed record per (bh,c): A,B,C,D,E,F=bsrc+bdst, 0.4*att, pad
// Lin[bh][6] = 0.6 * sum_c att_c * {A,B,C,D,E,F}_c
__global__ __launch_bounds__(256) void prep_kernel(
    const int* __restrict__ ei, const float* __restrict__ eattr,
    float* __restrict__ meansum, float* __restrict__ Lin, int* __restrict__ cnt,
    const float* __restrict__ Wsrc0, const float* __restrict__ bsrc0,
    const float* __restrict__ Wdst0, const float* __restrict__ bdst0,
    const float* __restrict__ Wedge0, const float* __restrict__ att0,
    const float* __restrict__ Wsrc1, const float* __restrict__ bsrc1,
    const float* __restrict__ Wdst1, const float* __restrict__ bdst1,
    const float* __restrict__ Wedge1, const float* __restrict__ att1,
    float* __restrict__ packed, int E)
{
    int tid = blockIdx.x * 256 + threadIdx.x;
    float s = 0.f;
    if (tid < E) {
        atomicAdd(&cnt[ei[E + tid]], 1);
        s = eattr[tid];
    }
    #pragma unroll
    for (int off = 32; off > 0; off >>= 1) s += __shfl_down(s, off, 64);
    __shared__ float wsum[4];
    int lane = threadIdx.x & 63, wid = threadIdx.x >> 6;
    if (lane == 0) wsum[wid] = s;
    __syncthreads();
    if (threadIdx.x == 0)
        atomicAdd(meansum, wsum[0] + wsum[1] + wsum[2] + wsum[3]);

    if (tid < 1024) {
        int b = tid >> 9;
        int hc = tid & 511;
        int c = hc & 127;
        int h = hc >> 7;
        int bh = b * 4 + h;
        const float* Ws = b ? Wsrc1 : Wsrc0;
        const float* bs = b ? bsrc1 : bsrc0;
        const float* Wd = b ? Wdst1 : Wdst0;
        const float* bd = b ? bdst1 : bdst0;
        const float* We = b ? Wedge1 : Wedge0;
        const float* at = b ? att1 : att0;
        float A = Ws[hc], B = Ws[512 + hc];
        float C = Wd[hc], D = Wd[512 + hc];
        float Ec = We[hc];
        float F = bs[hc] + bd[hc];
        float a = at[hc];
        float* r = packed + ((size_t)(bh * 128 + c)) * 8;
        r[0] = A; r[1] = B; r[2] = C; r[3] = D;
        r[4] = Ec; r[5] = F; r[6] = 0.4f * a; r[7] = 0.f;
        float sa = 0.6f * a;
        atomicAdd(&Lin[bh * 6 + 0], sa * A);
        atomicAdd(&Lin[bh * 6 + 1], sa * B);
        atomicAdd(&Lin[bh * 6 + 2], sa * C);
        atomicAdd(&Lin[bh * 6 + 3], sa * D);
        atomicAdd(&Lin[bh * 6 + 4], sa * Ec);
        atomicAdd(&Lin[bh * 6 + 5], sa * F);
    }
}

// ---------------- scan: exclusive prefix over (cnt+1), seeds cur ------------
__global__ __launch_bounds__(1024) void scan_kernel(const int* __restrict__ cnt,
                                                    int* __restrict__ rowptr,
                                                    int* __restrict__ cur, int N) {
    const int CH = 32;  // covers N up to 32768
    int t = threadIdx.x;
    int base = t * CH;
    int local[CH];
    int s = 0;
    #pragma unroll
    for (int i = 0; i < CH; ++i) {
        int idx = base + i;
        int v = (idx < N) ? cnt[idx] + 1 : 0;  // +1 = self loop
        local[i] = s;
        s += v;
    }
    __shared__ int sums[1024];
    sums[t] = s;
    __syncthreads();
    for (int off = 1; off < 1024; off <<= 1) {
        int v = (t >= off) ? sums[t - off] : 0;
        __syncthreads();
        sums[t] += v;
        __syncthreads();
    }
    int excl = sums[t] - s;
    #pragma unroll
    for (int i = 0; i < CH; ++i) {
        int idx = base + i;
        if (idx < N) {
            int v = excl + local[i];
            rowptr[idx] = v;
            cur[idx] = v;
        }
    }
    if (t == 1023) rowptr[N] = excl + s;
}

// ---------------- scatter: build CSR edge records {xs,xd} + ea --------------
__global__ __launch_bounds__(256) void scatter_kernel(
    const int* __restrict__ ei, const float* __restrict__ x,
    const float* __restrict__ eattr, const float* __restrict__ meansum,
    int* __restrict__ cur, float4* __restrict__ ed4, float* __restrict__ ea1,
    int N, int E) {
    int e = blockIdx.x * 256 + threadIdx.x;
    int Etot = E + N;
    if (e >= Etot) return;
    int src, dst;
    float ea;
    if (e < E) { src = ei[e]; dst = ei[E + e]; ea = eattr[e]; }
    else       { src = e - E; dst = src; ea = meansum[0] / (float)E; }
    int pos = atomicAdd(&cur[dst], 1);
    const float2* x2 = (const float2*)x;
    float2 xs = x2[src];
    float2 xd = x2[dst];
    ed4[pos] = make_float4(xs.x, xs.y, xd.x, xd.y);
    ea1[pos] = ea;
}

// ---------------- logits: weights in registers (launch_bounds caps 3/EU) ----
// lane = bh*8 + cg; lane owns channels [cg*16, cg*16+16) as 8 v2f pairs.
// logit = Lin[bh].(xs0,xs1,xd0,xd1,ea,1) + sum_c 0.4*att_c*|u_c|
// Writes p = exp(logit) at CSR position: p8[i*8+bh].
__global__ __launch_bounds__(256, 3) void logits_kernel(
    const float4* __restrict__ ed4,
    const float* __restrict__ ea1,
    const float* __restrict__ Lin,
    const float4* __restrict__ packed4,
    float* __restrict__ p8, int Etot)
{
    __shared__ __align__(16) float4 edlds[4][64];
    __shared__ float ealds[4][64];
    int t = threadIdx.x;
    int wid = t >> 6, lane = t & 63;
    int bh = lane >> 3, cg = lane & 7;

    v2f Av[8], Bv[8], Cv[8], Dv[8], Ev[8], Fv[8], Gv[8];
    int cbase = bh * 128 + cg * 16;
    #pragma unroll
    for (int p = 0; p < 8; ++p) {
        float4 wa0 = packed4[(cbase + 2 * p) * 2];
        float4 wa1 = packed4[(cbase + 2 * p) * 2 + 1];
        float4 wb0 = packed4[(cbase + 2 * p + 1) * 2];
        float4 wb1 = packed4[(cbase + 2 * p + 1) * 2 + 1];
        Av[p] = (v2f){wa0.x, wb0.x};
        Bv[p] = (v2f){wa0.y, wb0.y};
        Cv[p] = (v2f){wa0.z, wb0.z};
        Dv[p] = (v2f){wa0.w, wb0.w};
        Ev[p] = (v2f){wa1.x, wb1.x};
        Fv[p] = (v2f){wa1.y, wb1.y};
        Gv[p] = (v2f){wa1.z, wb1.z};
    }
    float L0 = Lin[bh * 6 + 0], L1 = Lin[bh * 6 + 1], L2 = Lin[bh * 6 + 2];
    float L3 = Lin[bh * 6 + 3], L4 = Lin[bh * 6 + 4], L5 = Lin[bh * 6 + 5];

    int base = (blockIdx.x * 4 + wid) * 64;
    {
        int i = base + lane;
        if (i < Etot) {
            edlds[wid][lane] = ed4[i];
            ealds[wid][lane] = ea1[i];
        }
    }
    __syncthreads();
    if (base >= Etot) return;
    int jmax = min(64, Etot - base);

    auto body = [&](int j) {
        float4 xv = edlds[wid][j];
        float eas = ealds[wid][j];
        v2f xs0 = {xv.x, xv.x}, xs1 = {xv.y, xv.y};
        v2f xd0 = {xv.z, xv.z}, xd1 = {xv.w, xv.w};
        v2f eav = {eas, eas};
        v2f acc = {0.f, 0.f};
        #pragma unroll
        for (int p = 0; p < 8; ++p) {
            v2f u = pkfma(Ev[p], eav, Fv[p]);
            u = pkfma(Av[p], xs0, u);
            u = pkfma(Bv[p], xs1, u);
            u = pkfma(Cv[p], xd0, u);
            u = pkfma(Dv[p], xd1, u);
            acc = pkfma(Gv[p], vabs(u), acc);
        }
        float s = acc.x + acc.y;
        s += __shfl_xor(s, 1);
        s += __shfl_xor(s, 2);
        s += __shfl_xor(s, 4);
        float lg = fmaf(L0, xv.x, fmaf(L1, xv.y, fmaf(L2, xv.z,
                   fmaf(L3, xv.w, fmaf(L4, eas, L5))))) + s;
        float pv = __expf(lg);
        if (cg == 0) p8[(size_t)(base + j) * 8 + bh] = pv;
    };

    if (jmax == 64) {
        #pragma unroll 4
        for (int j = 0; j < 64; ++j) body(j);
    } else {
        for (int j = 0; j < jmax; ++j) body(j);
    }
}

// ---------------- nodeS: per-node gather (coalesced CSR reads) --------------
__global__ __launch_bounds__(256) void nodeS_kernel(
    const int* __restrict__ rowptr, const float4* __restrict__ ed4,
    const float* __restrict__ p8, float* __restrict__ S, int N)
{
    int t = threadIdx.x;
    int g = t >> 3, bh = t & 7;
    int n = blockIdx.x * 32 + g;
    if (n >= N) return;
    int beg = rowptr[n], end = rowptr[n + 1];
    float s0 = 0.f, s1 = 0.f, sb = 0.f;
    for (int i = beg; i < end; ++i) {
        float4 ed = ed4[i];
        float p = p8[(size_t)i * 8 + bh];
        s0 = fmaf(p, ed.x, s0);
        s1 = fmaf(p, ed.y, s1);
        sb += p;
    }
    float* Sp = S + (size_t)n * 24 + bh * 3;
    Sp[0] = s0;
    Sp[1] = s1;
    Sp[2] = sb;
}

// ---------------- node: reconstruction + fuse matvec ------------------------
__global__ __launch_bounds__(256) void node_kernel(
    const float* __restrict__ x,
    const float* __restrict__ S,
    const float* __restrict__ Wsrc0, const float* __restrict__ bsrc0,
    const float* __restrict__ bias0, const float* __restrict__ Wres0,
    const float* __restrict__ Wsrc1, const float* __restrict__ bsrc1,
    const float* __restrict__ bias1, const float* __restrict__ Wres1,
    const float* __restrict__ Wfuse, const float* __restrict__ bfuse,
    float* __restrict__ out, int N)
{
    __shared__ __align__(16) float hbuf[NPB][2 * CC];
    int t = threadIdx.x;
    int c = t & (CC - 1);
    int half = t >> 7;  // 0 or 1
    int n0 = blockIdx.x * NPB;

    float w00[HH], w01[HH], wb0[HH], w10[HH], w11[HH], wb1[HH];
    #pragma unroll
    for (int h = 0; h < HH; ++h) {
        w00[h] = Wsrc0[h * CC + c];
        w01[h] = Wsrc0[512 + h * CC + c];
        wb0[h] = bsrc0[h * CC + c];
        w10[h] = Wsrc1[h * CC + c];
        w11[h] = Wsrc1[512 + h * CC + c];
        wb1[h] = bsrc1[h * CC + c];
    }
    float bi0 = bias0[c], bi1 = bias1[c];
    float r00 = Wres0[c], r01 = Wres0[CC + c];
    float r10 = Wres1[c], r11 = Wres1[CC + c];

    for (int ni = half; ni < NPB; ni += 2) {
        int n = n0 + ni;
        if (n < N) {
            float x0 = x[2 * n], x1 = x[2 * n + 1];
            const float* Sp = S + (size_t)n * 24;
            float h0v, h1v;
            {
                float acc = 0.f;
                #pragma unroll
                for (int h = 0; h < HH; ++h) {
                    float s0 = Sp[h * 3 + 0];
                    float s1 = Sp[h * 3 + 1];
                    float sb = Sp[h * 3 + 2];
                    float num = fmaf(w00[h], s0, fmaf(w01[h], s1, wb0[h] * sb));
                    acc += num / (sb + 1e-16f);
                }
                float o = fmaxf(acc * 0.25f + bi0, 0.f);
                h0v = o + x0 * r00 + x1 * r01;
            }
            {
                float acc = 0.f;
                #pragma unroll
                for (int h = 0; h < HH; ++h) {
                    float s0 = Sp[12 + h * 3 + 0];
                    float s1 = Sp[12 + h * 3 + 1];
                    float sb = Sp[12 + h * 3 + 2];
                    float num = fmaf(w10[h], s0, fmaf(w11[h], s1, wb1[h] * sb));
                    acc += num / (sb + 1e-16f);
                }
                float o = fmaxf(acc * 0.25f + bi1, 0.f);
                h1v = o + x0 * r10 + x1 * r11;
            }
            hbuf[ni][c] = h0v;
            hbuf[ni][CC + c] = h1v;
        }
    }
    __syncthreads();

    float acc[4];
    float bf = bfuse[c];
    #pragma unroll
    for (int j = 0; j < 4; ++j) acc[j] = bf;

    for (int i = 0; i < 2 * CC; i += 4) {
        float wv0 = Wfuse[(i + 0) * CC + c];
        float wv1 = Wfuse[(i + 1) * CC + c];
        float wv2 = Wfuse[(i + 2) * CC + c];
        float wv3 = Wfuse[(i + 3) * CC + c];
        #pragma unroll
        for (int j = 0; j < 4; ++j) {
            int ni = half * 4 + j;
            float4 hv = *reinterpret_cast<const float4*>(&hbuf[ni][i]);
            acc[j] = fmaf(hv.x, wv0, fmaf(hv.y, wv1,
                     fmaf(hv.z, wv2, fmaf(hv.w, wv3, acc[j]))));
        }
    }
    #pragma unroll
    for (int j = 0; j < 4; ++j) {
        int n = n0 + half * 4 + j;
        if (n < N) out[n * CC + c] = fmaxf(acc[j], 0.f);
    }
}

extern "C" void kernel_launch(void* const* d_in, const int* in_sizes, int n_in,
                              void* d_out, int out_size, void* d_ws, size_t ws_size,
                              hipStream_t stream) {
    const float* x      = (const float*)d_in[0];
    const int*   ei     = (const int*)d_in[1];
    const float* eattr  = (const float*)d_in[2];
    const float* Wsrc0  = (const float*)d_in[3];
    const float* bsrc0  = (const float*)d_in[4];
    const float* Wdst0  = (const float*)d_in[5];
    const float* bdst0  = (const float*)d_in[6];
    const float* Wedge0 = (const float*)d_in[7];
    const float* att0   = (const float*)d_in[8];
    const float* bias0  = (const float*)d_in[9];
    const float* Wres0  = (const float*)d_in[10];
    const float* Wsrc1  = (const float*)d_in[11];
    const float* bsrc1  = (const float*)d_in[12];
    const float* Wdst1  = (const float*)d_in[13];
    const float* bdst1  = (const float*)d_in[14];
    const float* Wedge1 = (const float*)d_in[15];
    const float* att1   = (const float*)d_in[16];
    const float* bias1  = (const float*)d_in[17];
    const float* Wres1  = (const float*)d_in[18];
    const float* Wfuse  = (const float*)d_in[19];
    const float* bfuse  = (const float*)d_in[20];
    float* out = (float*)d_out;

    int N = in_sizes[0] / 2;   // x is (N,2)
    int E = in_sizes[1] / 2;   // edge_index is (2,E)
    int Etot = E + N;

    // workspace layout; zero region = meansum(0..4) + Lin(64..256) + cnt
    size_t off = 0;
    float* meansum = (float*)((char*)d_ws + off);
    float* Lin     = (float*)((char*)d_ws + 64);   off += 256;
    int*   cnt     = (int*)((char*)d_ws + off);    off += roundup256((size_t)N * sizeof(int));
    size_t zero_bytes = off;
    int*   cur     = (int*)((char*)d_ws + off);    off += roundup256((size_t)N * sizeof(int));
    int*   rowptr  = (int*)((char*)d_ws + off);    off += roundup256((size_t)(N + 1) * sizeof(int));
    float* packed  = (float*)((char*)d_ws + off);  off += roundup256(8 * 128 * 8 * sizeof(float));
    float4* ed4    = (float4*)((char*)d_ws + off); off += roundup256((size_t)Etot * sizeof(float4));
    float* ea1     = (float*)((char*)d_ws + off);  off += roundup256((size_t)Etot * sizeof(float));
    float* p8      = (float*)((char*)d_ws + off);  off += roundup256((size_t)Etot * 8 * sizeof(float));
    float* S       = (float*)((char*)d_ws + off);  off += roundup256((size_t)24 * N * sizeof(float));

    hipMemsetAsync(d_ws, 0, zero_bytes, stream);

    prep_kernel<<<(E + 255) / 256, 256, 0, stream>>>(
        ei, eattr, meansum, Lin, cnt,
        Wsrc0, bsrc0, Wdst0, bdst0, Wedge0, att0,
        Wsrc1, bsrc1, Wdst1, bdst1, Wedge1, att1,
        packed, E);

    scan_kernel<<<1, 1024, 0, stream>>>(cnt, rowptr, cur, N);

    scatter_kernel<<<(Etot + 255) / 256, 256, 0, stream>>>(
        ei, x, eattr, meansum, cur, ed4, ea1, N, E);

    int nchunks = (Etot + 63) / 64;
    logits_kernel<<<(nchunks + 3) / 4, 256, 0, stream>>>(
        ed4, ea1, Lin, (const float4*)packed, p8, Etot);

    nodeS_kernel<<<(N + 31) / 32, 256, 0, stream>>>(rowptr, ed4, p8, S, N);

    node_kernel<<<(N + NPB - 1) / NPB, 256, 0, stream>>>(
        x, S,
        Wsrc0, bsrc0, bias0, Wres0,
        Wsrc1, bsrc1, bias1, Wres1,
        Wfuse, bfuse, out, N);
}